// Round 2
// baseline (2206.266 us; speedup 1.0000x reference)
//
#include <hip/hip_runtime.h>
#include <hip/hip_bf16.h>

#define T_STEPS 2048
#define BATCH   64
#define DIN     256
#define DH      256

// ---------------- Phase 1: xproj = x @ W_ih^T + (b_ih + b_hh) ----------------
#define P1_BM 128
#define P1_BN 128
#define P1_KC 32
#define P1_PAD 4   // keeps rows 16B-aligned so fragment reads stay ds_read_b128

__global__ __launch_bounds__(256) void xproj_kernel(
    const float* __restrict__ x, const float* __restrict__ W,
    const float* __restrict__ b_ih, const float* __restrict__ b_hh,
    float* __restrict__ out) {
  __shared__ float As[P1_KC][P1_BM + P1_PAD];  // [k][m] (transposed for b128 reads)
  __shared__ float Wt[P1_KC][P1_BN + P1_PAD];  // [k][j]
  const int tid = threadIdx.x;
  const int m0 = blockIdx.x * P1_BM;
  const int j0 = blockIdx.y * P1_BN;
  const int r0 = (tid >> 4) * 8;               // 8 output rows per thread
  const int c0 = (tid & 15) * 8;               // 8 output cols per thread
  float acc[8][8] = {};

  for (int kc = 0; kc < DIN; kc += P1_KC) {
    __syncthreads();
#pragma unroll
    for (int s = 0; s < 4; ++s) {
      int idx = s * 256 + tid;                 // 0..1023
      int row = idx >> 3;                      // m: 0..127
      int c4  = (idx & 7) << 2;                // k: 0..28
      float4 v = *reinterpret_cast<const float4*>(
          &x[(size_t)(m0 + row) * DIN + kc + c4]);
      As[c4 + 0][row] = v.x; As[c4 + 1][row] = v.y;
      As[c4 + 2][row] = v.z; As[c4 + 3][row] = v.w;
    }
#pragma unroll
    for (int s = 0; s < 4; ++s) {
      int idx = s * 256 + tid;
      int row = idx >> 3;                      // j: 0..127
      int c4  = (idx & 7) << 2;                // k: 0..28
      float4 v = *reinterpret_cast<const float4*>(
          &W[(size_t)(j0 + row) * DIN + kc + c4]);
      Wt[c4 + 0][row] = v.x; Wt[c4 + 1][row] = v.y;
      Wt[c4 + 2][row] = v.z; Wt[c4 + 3][row] = v.w;
    }
    __syncthreads();
#pragma unroll
    for (int k = 0; k < P1_KC; ++k) {
      float4 a0 = *reinterpret_cast<const float4*>(&As[k][r0]);
      float4 a1 = *reinterpret_cast<const float4*>(&As[k][r0 + 4]);
      float4 w0 = *reinterpret_cast<const float4*>(&Wt[k][c0]);
      float4 w1 = *reinterpret_cast<const float4*>(&Wt[k][c0 + 4]);
      float a[8] = {a0.x, a0.y, a0.z, a0.w, a1.x, a1.y, a1.z, a1.w};
      float wv[8] = {w0.x, w0.y, w0.z, w0.w, w1.x, w1.y, w1.z, w1.w};
#pragma unroll
      for (int i = 0; i < 8; ++i)
#pragma unroll
        for (int jj = 0; jj < 8; ++jj)
          acc[i][jj] = fmaf(a[i], wv[jj], acc[i][jj]);
    }
  }

  float bias[8];
#pragma unroll
  for (int jj = 0; jj < 8; ++jj) bias[jj] = b_ih[j0 + c0 + jj] + b_hh[j0 + c0 + jj];
#pragma unroll
  for (int i = 0; i < 8; ++i) {
    size_t m = (size_t)(m0 + r0 + i);
#pragma unroll
    for (int j4 = 0; j4 < 2; ++j4) {
      float4 v;
      v.x = acc[i][j4 * 4 + 0] + bias[j4 * 4 + 0];
      v.y = acc[i][j4 * 4 + 1] + bias[j4 * 4 + 1];
      v.z = acc[i][j4 * 4 + 2] + bias[j4 * 4 + 2];
      v.w = acc[i][j4 * 4 + 3] + bias[j4 * 4 + 3];
      *reinterpret_cast<float4*>(&out[m * DH + j0 + c0 + j4 * 4]) = v;
    }
  }
}

// ---------------- Phase 2: sequential scan, one WG per batch element --------
// Wave w owns 32 outputs; lane l: j = 32w + (l&31), k-half = l>>5.
// One barrier per step; h double-buffered in LDS; in-wave shfl reduction.
__global__ __launch_bounds__(512) void rnn_scan_kernel(
    const float* __restrict__ hx, const float* __restrict__ W_hh,
    float* __restrict__ outbuf,            // [T*B*DH], xproj in / h out (in place)
    float* __restrict__ hlast) {           // [B*DH]
  const int b    = blockIdx.x;
  const int tid  = threadIdx.x;            // 0..511
  const int wave = tid >> 6;               // 0..7
  const int lane = tid & 63;
  const int j    = wave * 32 + (lane & 31);
  const int kb   = (lane >> 5) * 128;      // my k-half base

  // 128 weights per lane: W_hh[j][kb .. kb+127]
  float4 w[32];
#pragma unroll
  for (int i = 0; i < 32; ++i)
    w[i] = *reinterpret_cast<const float4*>(&W_hh[(size_t)j * DH + kb + i * 4]);

  __shared__ float h_lds[2][DH];
  if (tid < DH) h_lds[0][tid] = hx[(size_t)b * DH + tid];

  const size_t stride_t = (size_t)BATCH * DH;
  const size_t base     = (size_t)b * DH;

  float xp_next = outbuf[base + j];        // t = 0 (all lanes; kh=1 dups kh=0)
  __syncthreads();

#pragma unroll 1
  for (int t = 0; t < T_STEPS; ++t) {
    const float xp = xp_next;
    if (t + 1 < T_STEPS)
      xp_next = outbuf[(size_t)(t + 1) * stride_t + base + j];   // prefetch

    const int cur = t & 1;
    const float4* __restrict__ hv =
        reinterpret_cast<const float4*>(&h_lds[cur][kb]);
    float p[8] = {};
#pragma unroll
    for (int i = 0; i < 32; ++i) {
      float4 h4 = hv[i];
      float a = p[i & 7];
      a = fmaf(w[i].x, h4.x, a);
      a = fmaf(w[i].y, h4.y, a);
      a = fmaf(w[i].z, h4.z, a);
      a = fmaf(w[i].w, h4.w, a);
      p[i & 7] = a;
    }
    float pa = ((p[0] + p[1]) + (p[2] + p[3])) + ((p[4] + p[5]) + (p[6] + p[7]));
    pa += __shfl_xor(pa, 32);              // combine the two k-halves in-wave

    const float s = pa + xp;
    // tanh(s) = 1 - 2/(e^{2s}+1); NaN-safe at +/-inf
    const float e = __expf(2.0f * s);
    const float h = 1.0f - 2.0f * __builtin_amdgcn_rcpf(e + 1.0f);

    if ((lane >> 5) == 0) {                // lanes 0..31 own distinct j
      h_lds[cur ^ 1][j] = h;
      outbuf[(size_t)t * stride_t + base + j] = h;
    }
    __syncthreads();
  }

  if (tid < DH) hlast[base + tid] = h_lds[0][tid];  // (2047+1)&1 == 0
}

extern "C" void kernel_launch(void* const* d_in, const int* in_sizes, int n_in,
                              void* d_out, int out_size, void* d_ws, size_t ws_size,
                              hipStream_t stream) {
  const float* x    = (const float*)d_in[0];
  const float* hx   = (const float*)d_in[1];
  const float* W_ih = (const float*)d_in[2];
  const float* W_hh = (const float*)d_in[3];
  const float* b_ih = (const float*)d_in[4];
  const float* b_hh = (const float*)d_in[5];
  float* out   = (float*)d_out;
  float* hlast = out + (size_t)T_STEPS * BATCH * DH;

  dim3 g1((T_STEPS * BATCH) / P1_BM, DH / P1_BN);
  xproj_kernel<<<g1, 256, 0, stream>>>(x, W_ih, b_ih, b_hh, out);

  rnn_scan_kernel<<<BATCH, 512, 0, stream>>>(hx, W_hh, out, hlast);
}

// Round 4
// 1786.324 us; speedup vs baseline: 1.2351x; 1.2351x over previous
//
#include <hip/hip_runtime.h>
#include <hip/hip_bf16.h>

#define T_STEPS 2048
#define BATCH   64
#define DIN     256
#define DH      256

// ---------------- Phase 1: xproj = x @ W_ih^T + (b_ih + b_hh) ----------------
#define P1_BM 128
#define P1_BN 128
#define P1_KC 32
#define P1_PAD 4   // keeps rows 16B-aligned so fragment reads stay ds_read_b128

__global__ __launch_bounds__(256) void xproj_kernel(
    const float* __restrict__ x, const float* __restrict__ W,
    const float* __restrict__ b_ih, const float* __restrict__ b_hh,
    float* __restrict__ out) {
  __shared__ float As[P1_KC][P1_BM + P1_PAD];  // [k][m]
  __shared__ float Wt[P1_KC][P1_BN + P1_PAD];  // [k][j]
  const int tid = threadIdx.x;
  const int m0 = blockIdx.x * P1_BM;
  const int j0 = blockIdx.y * P1_BN;
  const int r0 = (tid >> 4) * 8;
  const int c0 = (tid & 15) * 8;
  float acc[8][8] = {};

  for (int kc = 0; kc < DIN; kc += P1_KC) {
    __syncthreads();
#pragma unroll
    for (int s = 0; s < 4; ++s) {
      int idx = s * 256 + tid;
      int row = idx >> 3;
      int c4  = (idx & 7) << 2;
      float4 v = *reinterpret_cast<const float4*>(
          &x[(size_t)(m0 + row) * DIN + kc + c4]);
      As[c4 + 0][row] = v.x; As[c4 + 1][row] = v.y;
      As[c4 + 2][row] = v.z; As[c4 + 3][row] = v.w;
    }
#pragma unroll
    for (int s = 0; s < 4; ++s) {
      int idx = s * 256 + tid;
      int row = idx >> 3;
      int c4  = (idx & 7) << 2;
      float4 v = *reinterpret_cast<const float4*>(
          &W[(size_t)(j0 + row) * DIN + kc + c4]);
      Wt[c4 + 0][row] = v.x; Wt[c4 + 1][row] = v.y;
      Wt[c4 + 2][row] = v.z; Wt[c4 + 3][row] = v.w;
    }
    __syncthreads();
#pragma unroll
    for (int k = 0; k < P1_KC; ++k) {
      float4 a0 = *reinterpret_cast<const float4*>(&As[k][r0]);
      float4 a1 = *reinterpret_cast<const float4*>(&As[k][r0 + 4]);
      float4 w0 = *reinterpret_cast<const float4*>(&Wt[k][c0]);
      float4 w1 = *reinterpret_cast<const float4*>(&Wt[k][c0 + 4]);
      float a[8] = {a0.x, a0.y, a0.z, a0.w, a1.x, a1.y, a1.z, a1.w};
      float wv[8] = {w0.x, w0.y, w0.z, w0.w, w1.x, w1.y, w1.z, w1.w};
#pragma unroll
      for (int i = 0; i < 8; ++i)
#pragma unroll
        for (int jj = 0; jj < 8; ++jj)
          acc[i][jj] = fmaf(a[i], wv[jj], acc[i][jj]);
    }
  }

  float bias[8];
#pragma unroll
  for (int jj = 0; jj < 8; ++jj) bias[jj] = b_ih[j0 + c0 + jj] + b_hh[j0 + c0 + jj];
#pragma unroll
  for (int i = 0; i < 8; ++i) {
    size_t m = (size_t)(m0 + r0 + i);
#pragma unroll
    for (int j4 = 0; j4 < 2; ++j4) {
      float4 v;
      v.x = acc[i][j4 * 4 + 0] + bias[j4 * 4 + 0];
      v.y = acc[i][j4 * 4 + 1] + bias[j4 * 4 + 1];
      v.z = acc[i][j4 * 4 + 2] + bias[j4 * 4 + 2];
      v.w = acc[i][j4 * 4 + 3] + bias[j4 * 4 + 3];
      *reinterpret_cast<float4*>(&out[m * DH + j0 + c0 + j4 * 4]) = v;
    }
  }
}

// ---------------- Phase 2: sequential scan, one WG per batch element --------
// Thread layout: kg = lane&15 owns h[kg*16..+15]; jg = wave*4 + (lane>>4) owns
// j in [jg*8, jg*8+8). 128 FMA/lane/step but only 64B of h read per lane.
// 16-way k-reduction via 4-stage value-splitting butterfly (8 shfl/lane).
// h double-buffered in LDS (swizzled [chunk][kg][4] layout), 1 barrier/step.
__global__ __launch_bounds__(512) void rnn_scan_kernel(
    const float* __restrict__ hx, const float* __restrict__ W_hh,
    float* __restrict__ outbuf,            // [T*B*DH], xproj in / h out (in place)
    float* __restrict__ hlast) {           // [B*DH]
  const int b    = blockIdx.x;
  const int tid  = threadIdx.x;
  const int wave = tid >> 6;
  const int lane = tid & 63;
  const int kg   = lane & 15;              // k-group: h[kg*16 .. kg*16+15]
  const int jg   = wave * 4 + (lane >> 4); // j-group: j = jg*8 + r
  // after the butterfly this lane owns j = jg*8 + (4*b0 + 2*b1 + b2)
  const int jred = jg * 8 + ((lane & 1) << 2) + (lane & 2) + ((lane >> 2) & 1);

  // weights: w[r][c] = W_hh[jg*8+r][kg*16 + 4c .. +3]
  float4 w[8][4];
#pragma unroll
  for (int r = 0; r < 8; ++r)
#pragma unroll
    for (int c = 0; c < 4; ++c)
      w[r][c] = *reinterpret_cast<const float4*>(
          &W_hh[(size_t)(jg * 8 + r) * DH + kg * 16 + c * 4]);

  // h storage: hbuf[buf][chunk][kg][4]; h[kg*16 + 4c + e] -> hbuf[.][c][kg][e]
  __shared__ float hbuf[2][4][16][4];
  if (tid < DH) hbuf[0][(tid >> 2) & 3][tid >> 4][tid & 3] = hx[(size_t)b * DH + tid];

  const size_t stride_t = (size_t)BATCH * DH;
  const size_t base     = (size_t)b * DH;

  float xp_next = outbuf[base + jred];     // t = 0 (dup across bit3 harmless)
  __syncthreads();

#pragma unroll 1
  for (int t = 0; t < T_STEPS; ++t) {
    const float xp = xp_next;
    if (t + 1 < T_STEPS)
      xp_next = outbuf[(size_t)(t + 1) * stride_t + base + jred];

    const int cur = t & 1;
    float4 hc[4];
#pragma unroll
    for (int c = 0; c < 4; ++c)
      hc[c] = *reinterpret_cast<const float4*>(&hbuf[cur][c][kg][0]);

    float p[8];
#pragma unroll
    for (int r = 0; r < 8; ++r) {
      float a = 0.f;
#pragma unroll
      for (int c = 0; c < 4; ++c) {
        a = fmaf(w[r][c].x, hc[c].x, a);
        a = fmaf(w[r][c].y, hc[c].y, a);
        a = fmaf(w[r][c].z, hc[c].z, a);
        a = fmaf(w[r][c].w, hc[c].w, a);
      }
      p[r] = a;
    }

    // 16-way reduce-scatter butterfly, cheap masks first (xor1/2 -> DPP)
    const bool b0 = lane & 1, b1 = lane & 2, b2 = lane & 4;
    float q[4];
#pragma unroll
    for (int i = 0; i < 4; ++i) {
      float sent = b0 ? p[i] : p[4 + i];
      float recv = __shfl_xor(sent, 1);
      q[i] = (b0 ? p[4 + i] : p[i]) + recv;
    }
    float u[2];
#pragma unroll
    for (int i = 0; i < 2; ++i) {
      float sent = b1 ? q[i] : q[2 + i];
      float recv = __shfl_xor(sent, 2);
      u[i] = (b1 ? q[2 + i] : q[i]) + recv;
    }
    float sent = b2 ? u[0] : u[1];
    float v = (b2 ? u[1] : u[0]) + __shfl_xor(sent, 4);
    v += __shfl_xor(v, 8);                 // lanes differing in bit3 share jred

    const float s = v + xp;
    const float e = __expf(2.0f * s);      // tanh = 1 - 2/(e^{2s}+1), inf-safe
    const float h = 1.0f - 2.0f * __builtin_amdgcn_rcpf(e + 1.0f);

    if (!(lane & 8)) {                     // one writer per jred
      hbuf[cur ^ 1][(jred >> 2) & 3][jred >> 4][jred & 3] = h;
      outbuf[(size_t)t * stride_t + base + jred] = h;
    }
    __syncthreads();
  }

  if (tid < DH)                            // final h lives in buf 0
    hlast[base + tid] = hbuf[0][(tid >> 2) & 3][tid >> 4][tid & 3];
}

extern "C" void kernel_launch(void* const* d_in, const int* in_sizes, int n_in,
                              void* d_out, int out_size, void* d_ws, size_t ws_size,
                              hipStream_t stream) {
  const float* x    = (const float*)d_in[0];
  const float* hx   = (const float*)d_in[1];
  const float* W_ih = (const float*)d_in[2];
  const float* W_hh = (const float*)d_in[3];
  const float* b_ih = (const float*)d_in[4];
  const float* b_hh = (const float*)d_in[5];
  float* out   = (float*)d_out;
  float* hlast = out + (size_t)T_STEPS * BATCH * DH;

  dim3 g1((T_STEPS * BATCH) / P1_BM, DH / P1_BN);
  xproj_kernel<<<g1, 256, 0, stream>>>(x, W_ih, b_ih, b_hh, out);

  rnn_scan_kernel<<<BATCH, 512, 0, stream>>>(hx, W_hh, out, hlast);
}